// Round 10
// baseline (484.943 us; speedup 1.0000x reference)
//
#include <hip/hip_runtime.h>

// MLA forward. Inputs f32, internal bf16 MFMA 16x16x32, output f32.
// R17: attn reverted to R13 verbatim (119us; R14/15/16 restructures all
// regressed). New: GEMM epilogue fusion kills the re-layout tail:
//  - mode 2 (q-GEMM): writes q_fin directly. Tiles are 128-wide so a block
//    is uniformly nope (scale by QS) or rope (lane-pair shfl_xor(1) gives
//    the (xr,xi) partner; cosT/sinT lookup per row). k_q_rope deleted.
//  - mode 3 (kvb-GEMM): writes k_full (k_nope cols) and tile-major v_t
//    (V cols, packed u16x4 stores) from the accumulator. k_build_k and
//    k_v_t deleted; tiny k_pefill fills k_full's k_pe region.
// GEMM core = R13 counted-vmcnt pipeline, unchanged.

typedef __attribute__((ext_vector_type(8))) short short8;
typedef __attribute__((ext_vector_type(4))) float floatx4;
typedef unsigned short u16;
typedef unsigned int u32;

__device__ __forceinline__ float bf2f(u16 u){ u32 x=((u32)u)<<16; return __builtin_bit_cast(float,x); }
__device__ __forceinline__ u16 f2bf(float f){ u32 x=__builtin_bit_cast(u32,f); return (u16)((x + 0x7fffu + ((x>>16)&1u))>>16); }

__device__ __forceinline__ floatx4 mfma16(short8 a, short8 b, floatx4 c){
  return __builtin_amdgcn_mfma_f32_16x16x32_bf16(a,b,c,0,0,0);
}

// async global->LDS, 16B per lane. LDS dest = wave-uniform base + lane*16.
__device__ __forceinline__ void gl_lds16(const u16* g, u16* l){
  __builtin_amdgcn_global_load_lds((const __attribute__((address_space(1))) void*)g,
                                   (__attribute__((address_space(3))) void*)l, 16, 0, 0);
}

// ---------- f32 -> bf16 elementwise (for x) ----------
__global__ __launch_bounds__(256)
void k_f2b(const float* __restrict__ in, u16* __restrict__ out, size_t n){
  size_t i = ((size_t)blockIdx.x*256 + threadIdx.x)*4;
  if(i >= n) return;
  float4 v = *(const float4*)(in + i);
  out[i+0] = f2bf(v.x); out[i+1] = f2bf(v.y); out[i+2] = f2bf(v.z); out[i+3] = f2bf(v.w);
}

// ---------- transpose + convert: f32 [K,N] -> bf16 [N,K] ----------
__global__ void k_transpose(const float* __restrict__ in, u16* __restrict__ out, int K, int N){
  __shared__ u16 tile[32][33];
  const int kb = blockIdx.y*32, nb = blockIdx.x*32;
  const int tx = threadIdx.x, ty = threadIdx.y;
#pragma unroll
  for(int i=0;i<4;i++) tile[ty+i*8][tx] = f2bf(in[(size_t)(kb+ty+i*8)*N + nb + tx]);
  __syncthreads();
#pragma unroll
  for(int i=0;i<4;i++) out[(size_t)(nb+ty+i*8)*K + kb + tx] = tile[tx][ty+i*8];
}

// ---------- rope table (fp64 for large-angle accuracy) ----------
__global__ void k_rope_table(float* __restrict__ cosT, float* __restrict__ sinT){
  int idx = blockIdx.x*256 + threadIdx.x;
  if(idx >= 2048*64) return;
  int p = idx>>6, i = idx&63;
  double freq = pow(10000.0, -(double)(2*i)/128.0) * 40.0;
  float ff = (float)freq;
  float ang = (float)((double)p * (double)ff);
  cosT[idx] = (float)cos((double)ang);
  sinT[idx] = (float)sin((double)ang);
}

// ---------- GEMM: A[M,K] bf16 @ Bt[N,K] bf16, counted-vmcnt pipeline ----------
// MODE 0: C bf16 [M,N].  MODE 1: C f32 [M,N].
// MODE 2: q epilogue -> q_fin[(b*16+h)*2048+sidx][256], nope*QS / rope.
// MODE 3: kvb epilogue -> k_full (cols<128 of each 256-group) + v_t (cols>=128).
template<int MODE>
__global__ __launch_bounds__(256)
void k_gemm_bt(const u16* __restrict__ A, const u16* __restrict__ Bt, void* __restrict__ Cout,
               int M, int N, int K,
               const int* __restrict__ pid, const float* __restrict__ cosT,
               const float* __restrict__ sinT, u16* __restrict__ out2){
  __shared__ __align__(16) u16 ls[2][2][8192];   // [dbuf][A,B][128*64] = 64 KiB
  const int t = threadIdx.x;
  const int nbx = N>>7;
  const int nwg = gridDim.x;
  const int swz = (blockIdx.x & 7)*(nwg>>3) + (blockIdx.x>>3);
  const int by = swz / nbx, bx = swz - by*nbx;
  const int m0 = by*128, n0 = bx*128;
  const int wv = t>>6, ln = t&63;
  const int wr = (wv>>1)*64, wc = (wv&1)*64;
  const int fr = ln&15, gq = ln>>4;
  const int srow = t>>3;
  const int suX = (t&7) ^ (srow&7);
  const u16* Ag = A + (size_t)(m0 + srow)*K + suX*8;
  const u16* Bg = Bt + (size_t)(n0 + srow)*K + suX*8;
  const int nt = K>>6;
  const int uk0 = ((gq)     ^ (fr&7))*8;
  const int uk1 = ((4|gq)   ^ (fr&7))*8;
  int raw[4], rbw[4];
#pragma unroll
  for(int i=0;i<4;i++){ raw[i] = (wr+i*16+fr)*64; rbw[i] = (wc+i*16+fr)*64; }

  floatx4 acc[4][4];
#pragma unroll
  for(int i=0;i<4;i++)
#pragma unroll
    for(int j=0;j<4;j++) acc[i][j] = (floatx4){0.f,0.f,0.f,0.f};

  auto stage = [&](int buf, int kt){
    const int k0 = kt*64;
#pragma unroll
    for(int j=0;j<4;j++) gl_lds16(Ag + (size_t)(j*32)*K + k0, &ls[buf][0][j*2048 + t*8]);
#pragma unroll
    for(int j=0;j<4;j++) gl_lds16(Bg + (size_t)(j*32)*K + k0, &ls[buf][1][j*2048 + t*8]);
  };

  stage(0, 0);
  stage(1, 1);
  asm volatile("s_waitcnt vmcnt(8)" ::: "memory");
  __builtin_amdgcn_sched_barrier(0);
  __builtin_amdgcn_s_barrier();
  __builtin_amdgcn_sched_barrier(0);

  for(int kt=0; kt<nt; kt++){
    const int buf = kt&1;
    const u16* LA = &ls[buf][0][0];
    const u16* LB = &ls[buf][1][0];
    __builtin_amdgcn_s_setprio(1);
#pragma unroll
    for(int ks=0; ks<2; ks++){
      const int uk = ks ? uk1 : uk0;
      short8 af[4], bf[4];
#pragma unroll
      for(int i=0;i<4;i++) af[i] = *(const short8*)&LA[raw[i] + uk];
#pragma unroll
      for(int i=0;i<4;i++) bf[i] = *(const short8*)&LB[rbw[i] + uk];
#pragma unroll
      for(int mi=0;mi<4;mi++)
#pragma unroll
        for(int ni=0;ni<4;ni++) acc[mi][ni] = mfma16(af[mi], bf[ni], acc[mi][ni]);
    }
    __builtin_amdgcn_s_setprio(0);
    if(kt+1 < nt){
      asm volatile("s_waitcnt lgkmcnt(0)" ::: "memory");
      __builtin_amdgcn_sched_barrier(0);
      __builtin_amdgcn_s_barrier();
      __builtin_amdgcn_sched_barrier(0);
      if(kt+2 < nt){
        stage(buf, kt+2);
        asm volatile("s_waitcnt vmcnt(8)" ::: "memory");
      } else {
        asm volatile("s_waitcnt vmcnt(0)" ::: "memory");
      }
      __builtin_amdgcn_sched_barrier(0);
      __builtin_amdgcn_s_barrier();
      __builtin_amdgcn_sched_barrier(0);
    }
  }

  const int r0 = gq*4, c0 = fr;
  if(MODE <= 1){
#pragma unroll
    for(int mi=0;mi<4;mi++)
#pragma unroll
      for(int ni=0;ni<4;ni++){
        const int row = m0 + wr + mi*16 + r0;
        const int col = n0 + wc + ni*16 + c0;
#pragma unroll
        for(int r=0;r<4;r++){
          float v = acc[mi][ni][r];
          if(MODE==1) ((float*)Cout)[(size_t)(row+r)*N + col] = v;
          else        ((u16*)Cout)[(size_t)(row+r)*N + col] = f2bf(v);
        }
      }
  } else if(MODE == 2){
    // q_fin epilogue. col = n0+wc+ni*16+c0; h = col>>8; d = col&255.
    // block uniform: rope iff (n0&128)!=0 (wc+ni*16+c0 <= 127).
    const float QS = (float)(0.08838834764831845 * 1.4426950408889634);
    u16* qf = (u16*)Cout;
    const bool rope = (n0 & 128) != 0;
#pragma unroll
    for(int mi=0;mi<4;mi++)
#pragma unroll
      for(int ni=0;ni<4;ni++){
        const int row = m0 + wr + mi*16 + r0;
        const int col = n0 + wc + ni*16 + c0;
        const int h = col>>8, d = col&255;
#pragma unroll
        for(int r=0;r<4;r++){
          const int tok = row + r;
          const int b = tok>>11, sidx = tok&2047;
          float v = acc[mi][ni][r];
          float res;
          if(rope){
            const int p = pid[sidx];
            const int i = (d-128)>>1;
            float c = cosT[p*64+i], sn = sinT[p*64+i];
            float partner = __shfl_xor(v, 1);
            if((c0&1)==0) res = v*c - partner*sn;   // xr = v, xi = partner
            else          res = partner*sn + v*c;   // xr = partner, xi = v
          } else {
            res = v;
          }
          qf[(((size_t)(b*16 + h))*2048 + sidx)*256 + d] = f2bf(res*QS);
        }
      }
  } else {
    // MODE 3: kvb epilogue. col = kvh*256 + dd. k_nope iff (n0&128)==0.
    u16* kfull = (u16*)Cout;   // [b][kvh][s][256], dd<128 region
    const bool isv = (n0 & 128) != 0;
#pragma unroll
    for(int mi=0;mi<4;mi++)
#pragma unroll
      for(int ni=0;ni<4;ni++){
        const int row = m0 + wr + mi*16 + r0;
        const int col = n0 + wc + ni*16 + c0;
        const int kvh = (col>>8)&7, dd = col&255;
        if(!isv){
#pragma unroll
          for(int r=0;r<4;r++){
            const int tok = row + r;
            const int b = tok>>11, sidx = tok&2047;
            kfull[(((size_t)(b*8 + kvh))*2048 + sidx)*256 + dd] = f2bf(acc[mi][ni][r]);
          }
        } else {
          // v_t[((bk*64 + kt)*128 + hd)*32 + kv], 4 consecutive kv -> u16x4
          const int tok = row;           // rows row..row+3 share tile (kv%4==0)
          const int b = tok>>11, sidx = tok&2047;
          const int kt = sidx>>5, kv = sidx&31;
          const int hd = dd - 128;
          const size_t base = (((size_t)(b*8 + kvh)*64 + kt)*128 + hd)*32 + kv;
          u32 lo = (u32)f2bf(acc[mi][ni][0]) | ((u32)f2bf(acc[mi][ni][1])<<16);
          u32 hi = (u32)f2bf(acc[mi][ni][2]) | ((u32)f2bf(acc[mi][ni][3])<<16);
          uint2 pk; pk.x = lo; pk.y = hi;
          *(uint2*)&out2[base] = pk;
        }
      }
  }
}

// ---------- layernorm(kv[:512]) -> bf16 ; rope(kv[512:640]) -> k_pe bf16 ----------
__global__ __launch_bounds__(256)
void k_ln_rope(const float* __restrict__ kv, const float* __restrict__ scale,
               const int* __restrict__ pid, const float* __restrict__ cosT,
               const float* __restrict__ sinT, u16* __restrict__ kv_cn, u16* __restrict__ k_pe){
  const int tok = blockIdx.x;
  const int t = threadIdx.x;
  const float* row = kv + (size_t)tok*640;
  float v0 = row[2*t], v1 = row[2*t+1];
  float s = v0+v1, ss = v0*v0+v1*v1;
#pragma unroll
  for(int off=32; off>=1; off>>=1){ s += __shfl_xor(s,off); ss += __shfl_xor(ss,off); }
  __shared__ float red[8];
  if((t&63)==0){ red[t>>6]=s; red[4+(t>>6)]=ss; }
  __syncthreads();
  float S4 = red[0]+red[1]+red[2]+red[3];
  float SS4 = red[4]+red[5]+red[6]+red[7];
  float mean = S4*(1.f/512.f);
  float var = SS4*(1.f/512.f) - mean*mean;
  float inv = rsqrtf(var + 1e-5f);
  kv_cn[(size_t)tok*512 + 2*t]   = f2bf((v0-mean)*inv*scale[2*t]);
  kv_cn[(size_t)tok*512 + 2*t+1] = f2bf((v1-mean)*inv*scale[2*t+1]);
  if(t < 128){
    const int sidx = tok & 2047;
    const int p = pid[sidx];
    const int i = t>>1;
    float c = cosT[p*64+i], sn = sinT[p*64+i];
    float xr = row[512+2*i], xi = row[512+2*i+1];
    float val = (t&1) ? (xr*sn + xi*c) : (xr*c - xi*sn);
    k_pe[(size_t)tok*128 + t] = f2bf(val);
  }
}

// ---------- fill k_full[..][128..256) from k_pe ----------
__global__ __launch_bounds__(128)
void k_pefill(const u16* __restrict__ k_pe, u16* __restrict__ k_full){
  const int tok = blockIdx.x;
  const int b = tok>>11, sidx = tok&2047;
  const int t = threadIdx.x;
  const int kh = t>>4, seg = t&15;
  short8 v = *(const short8*)(k_pe + (size_t)tok*128 + seg*8);
  *(short8*)(k_full + (((size_t)(b*8 + kh))*2048 + sidx)*256 + 128 + seg*8) = v;
}

// ---------- flash attention (R13 verbatim): XCD-swizzled, balanced, m=2 ----------
__global__ __launch_bounds__(128, 2)
void k_attn(const u16* __restrict__ q_fin, const u16* __restrict__ k_full,
            const u16* __restrict__ v_t, u16* __restrict__ attn){
  __shared__ __align__(16) u16 lsK[2*8192];   // 32768 B : 2 x [32][256] swizzled
  __shared__ __align__(16) u16 lsP[2*32*40];  //  5120 B : per-wave [32][40]
  const int blk = blockIdx.x;
  const int kvh = blk&7;
  const int i  = blk>>3;          // 0..127
  const int j  = i>>5;            // 0..3
  const int mm = i&31;
  const int s  = mm>>2;           // 0..7
  int qt;
  if(j==0)      qt = s;
  else if(j==1) qt = 31 - s;
  else if(j==2) qt = 8 + s;
  else          qt = 23 - s;
  const int bb = (mm>>1)&1;
  const int hp = mm&1;
  const int h  = kvh*2 + hp;
  const int t = threadIdx.x, wv = t>>6, ln = t&63;
  const int fq = ln&15, gq = ln>>4;
  const u16* kbase = k_full + ((size_t)(bb*8 + kvh))*2048*256;
  const u16* vbase = v_t + ((size_t)(bb*8 + kvh))*128*2048;
  u16* Pw = &lsP[wv*32*40];

  int soff[8];
#pragma unroll
  for(int s8=0;s8<8;s8++){
    int o = s8*2048 + t*16;
    int row = o>>9, colb = o&511;
    soff[s8] = row*512 + (colb ^ ((row&7)<<4));
  }
  const int swz = (fq&7)<<4;
  int cb[8];
#pragma unroll
  for(int c=0;c<8;c++) cb[c] = (gq*16 + c*64) ^ swz;
  const int rowb = fq*512;
  const u16* vfp = vbase + (size_t)fq*32 + gq*8;

  const int last = 2*qt + 1;
  short8 qf[2][8];
#pragma unroll
  for(int m=0;m<2;m++){
    const u16* qb = q_fin + (((size_t)(bb*16 + h))*2048 + qt*64 + wv*32 + m*16 + fq)*256;
#pragma unroll
    for(int c=0;c<8;c++) qf[m][c] = *(const short8*)(qb + c*32 + gq*8);
  }
  floatx4 oacc[2][8];
#pragma unroll
  for(int m=0;m<2;m++)
#pragma unroll
    for(int ii=0;ii<8;ii++) oacc[m][ii] = (floatx4){0.f,0.f,0.f,0.f};
  float mprev0 = -3e38f, mprev1 = -3e38f, lsum0 = 0.f, lsum1 = 0.f;

#pragma unroll
  for(int s8=0;s8<8;s8++)
    gl_lds16((const u16*)((const char*)kbase + soff[s8]), &lsK[s8*1024 + wv*512]);
  __syncthreads();

  int cur = 0;
  for(int kt=0; kt<=last; kt++){
    if(kt < last){
      const char* ktile = (const char*)kbase + (size_t)(kt+1)*16384;
      u16* kdst = &lsK[(cur^1)*8192];
#pragma unroll
      for(int s8=0;s8<8;s8++)
        gl_lds16((const u16*)(ktile + soff[s8]), kdst + s8*1024 + wv*512);
    }
    short8 vf[8];
#pragma unroll
    for(int hs=0;hs<8;hs++)
      vf[hs] = *(const short8*)(vfp + (size_t)kt*4096 + hs*512);

    const char* Kc = (const char*)lsK + cur*16384;
    floatx4 sc[2][2];
#pragma unroll
    for(int m=0;m<2;m++)
#pragma unroll
      for(int ns=0;ns<2;ns++) sc[m][ns] = (floatx4){0.f,0.f,0.f,0.f};
#pragma unroll
    for(int ns=0;ns<2;ns++){
#pragma unroll
      for(int c=0;c<8;c++){
        short8 kf = *(const short8*)(Kc + ns*8192 + rowb + cb[c]);
        sc[0][ns] = mfma16(kf, qf[0][c], sc[0][ns]);
        sc[1][ns] = mfma16(kf, qf[1][c], sc[1][ns]);
      }
    }
    if(kt >= 2*qt){
      const int off = (kt - 2*qt)*32;
#pragma unroll
      for(int m=0;m<2;m++){
        const int qloc = wv*32 + m*16 + fq;
#pragma unroll
        for(int ns=0;ns<2;ns++)
#pragma unroll
          for(int r=0;r<4;r++)
            if(off + ns*16 + gq*4 + r > qloc) sc[m][ns][r] = -1e30f;
      }
    }
    float ml0 = -3e38f, ml1 = -3e38f;
#pragma unroll
    for(int ns=0;ns<2;ns++)
#pragma unroll
      for(int r=0;r<4;r++){ ml0 = fmaxf(ml0, sc[0][ns][r]); ml1 = fmaxf(ml1, sc[1][ns][r]); }
    ml0 = fmaxf(ml0, __shfl_xor(ml0, 16)); ml0 = fmaxf(ml0, __shfl_xor(ml0, 32));
    ml1 = fmaxf(ml1, __shfl_xor(ml1, 16)); ml1 = fmaxf(ml1, __shfl_xor(ml1, 32));
    if(__any((ml0 > mprev0 + 8.f) || (ml1 > mprev1 + 8.f))){
      const float mn0 = fmaxf(mprev0, ml0), mn1 = fmaxf(mprev1, ml1);
      const float a0 = exp2f(mprev0 - mn0), a1 = exp2f(mprev1 - mn1);
      lsum0 *= a0; lsum1 *= a1;
      float aO0[4], aO1[4];
#pragma unroll
      for(int r=0;r<4;r++){ aO0[r] = __shfl(a0, gq*4 + r); aO1[r] = __shfl(a1, gq*4 + r); }
#pragma unroll
      for(int hs=0;hs<8;hs++)
#pragma unroll
        for(int r=0;r<4;r++){ oacc[0][hs][r] *= aO0[r]; oacc[1][hs][r] *= aO1[r]; }
      mprev0 = mn0; mprev1 = mn1;
    }
    float ps0 = 0.f, ps1 = 0.f;
#pragma unroll
    for(int ns=0;ns<2;ns++)
#pragma unroll
      for(int r=0;r<4;r++){
        float p0 = exp2f(sc[0][ns][r] - mprev0);
        float p1 = exp2f(sc[1][ns][r] - mprev1);
        sc[0][ns][r] = p0; sc[1][ns][r] = p1;
        ps0 += p0; ps1 += p1;
      }
    ps0 += __shfl_xor(ps0, 16); ps0 += __shfl_xor(ps0, 32);
    ps1 += __shfl_xor(ps1, 16); ps1 += __shfl_xor(ps1, 32);
    lsum0 += ps0; lsum1 += ps1;

#pragma unroll
    for(int m=0;m<2;m++)
#pragma unroll
      for(int ns=0;ns<2;ns++){
        u32 p01, p23;
        asm("v_cvt_pk_bf16_f32 %0, %1, %2" : "=v"(p01) : "v"(sc[m][ns][0]), "v"(sc[m][ns][1]));
        asm("v_cvt_pk_bf16_f32 %0, %1, %2" : "=v"(p23) : "v"(sc[m][ns][2]), "v"(sc[m][ns][3]));
        uint2 pk; pk.x = p01; pk.y = p23;
        *(uint2*)&Pw[(m*16 + fq)*40 + ns*16 + gq*4] = pk;
      }
    __builtin_amdgcn_s_waitcnt(0xC07F);  // lgkmcnt(0): P visible to own wave

#pragma unroll
    for(int m=0;m<2;m++){
      short8 pa = *(const short8*)&Pw[(m*16 + fq)*40 + gq*8];
#pragma unroll
      for(int hs=0;hs<8;hs++)
        oacc[m][hs] = mfma16(pa, vf[hs], oacc[m][hs]);
    }
    __syncthreads();
    cur ^= 1;
  }
  const float i0 = 1.f / lsum0, i1 = 1.f / lsum1;
  float iO0[4], iO1[4];
#pragma unroll
  for(int r=0;r<4;r++){ iO0[r] = __shfl(i0, gq*4 + r); iO1[r] = __shfl(i1, gq*4 + r); }
#pragma unroll
  for(int m=0;m<2;m++)
#pragma unroll
    for(int hs=0;hs<8;hs++)
#pragma unroll
      for(int r=0;r<4;r++){
        const int qi = qt*64 + wv*32 + m*16 + gq*4 + r;
        float sc_ = (m==0) ? iO0[r] : iO1[r];
        attn[(((size_t)(bb*2048 + qi))*16 + h)*128 + hs*16 + fq] = f2bf(oacc[m][hs][r]*sc_);
      }
}

extern "C" void kernel_launch(void* const* d_in, const int* in_sizes, int n_in,
                              void* d_out, int out_size, void* d_ws, size_t ws_size,
                              hipStream_t stream){
  const float* x    = (const float*)d_in[0];
  const float* wq   = (const float*)d_in[1];
  const float* wkva = (const float*)d_in[2];
  const float* kvsc = (const float*)d_in[3];
  const float* wkvb = (const float*)d_in[4];
  const float* wo   = (const float*)d_in[5];
  const int* pid  = (const int*)d_in[7];
  float* out = (float*)d_out;

  char* w = (char*)d_ws;
  size_t off = 0;
  auto alloc = [&](size_t bytes)->void*{
    void* p = (void*)(w + off);
    off += (bytes + 255) & ~(size_t)255;
    return p;
  };
  u16*   x_bf   = (u16*)alloc((size_t)4096*2048*2);
  u16*   wq_t   = (u16*)alloc((size_t)4096*2048*2);
  u16*   wkva_t = (u16*)alloc((size_t)640*2048*2);
  u16*   wkvb_t = (u16*)alloc((size_t)2048*512*2);
  u16*   wo_t   = (u16*)alloc((size_t)2048*2048*2);
  float* cosT   = (float*)alloc((size_t)2048*64*4);
  float* sinT   = (float*)alloc((size_t)2048*64*4);
  float* kvf    = (float*)alloc((size_t)4096*640*4);
  u16*   kv_cn  = (u16*)alloc((size_t)4096*512*2);
  u16*   k_pe   = (u16*)alloc((size_t)4096*128*2);
  u16*   q_fin  = (u16*)alloc((size_t)4096*4096*2);
  u16*   k_full = (u16*)alloc((size_t)2*8*2048*256*2);
  u16*   v_t    = (u16*)alloc((size_t)2*8*128*2048*2);
  u16*   attn   = (u16*)alloc((size_t)4096*2048*2);

  k_f2b<<<8192, 256, 0, stream>>>(x, x_bf, (size_t)4096*2048);
  k_transpose<<<dim3(128, 64), dim3(32,8), 0, stream>>>(wq,   wq_t,   2048, 4096);
  k_transpose<<<dim3(20,  64), dim3(32,8), 0, stream>>>(wkva, wkva_t, 2048, 640);
  k_transpose<<<dim3(64,  16), dim3(32,8), 0, stream>>>(wkvb, wkvb_t, 512,  2048);
  k_transpose<<<dim3(64,  64), dim3(32,8), 0, stream>>>(wo,   wo_t,   2048, 2048);
  k_rope_table<<<512, 256, 0, stream>>>(cosT, sinT);

  // q projection + rope + layout, fused
  k_gemm_bt<2><<<1024, 256, 0, stream>>>(x_bf, wq_t, q_fin, 4096, 4096, 2048,
                                         pid, cosT, sinT, nullptr);
  k_gemm_bt<1><<<160,  256, 0, stream>>>(x_bf, wkva_t, kvf, 4096, 640, 2048,
                                         nullptr, nullptr, nullptr, nullptr);
  k_ln_rope<<<4096, 256, 0, stream>>>(kvf, kvsc, pid, cosT, sinT, kv_cn, k_pe);
  // kv_b projection + k_full/v_t scatter, fused
  k_gemm_bt<3><<<512,  256, 0, stream>>>(kv_cn, wkvb_t, k_full, 4096, 2048, 512,
                                         nullptr, nullptr, nullptr, v_t);
  k_pefill<<<4096, 128, 0, stream>>>(k_pe, k_full);
  k_attn<<<1024, 128, 0, stream>>>(q_fin, k_full, v_t, attn);
  k_gemm_bt<1><<<512,  256, 0, stream>>>(attn, wo_t, out, 4096, 2048, 2048,
                                         nullptr, nullptr, nullptr, nullptr);
}

// Round 11
// 455.254 us; speedup vs baseline: 1.0652x; 1.0652x over previous
//
#include <hip/hip_runtime.h>

// MLA forward. Inputs f32, internal bf16 MFMA 16x16x32, output f32.
// R18: GEMM occupancy fix. R17 counters: q-GEMM 122us, MfmaUtil 23%,
// Occupancy 17% (64KB LDS -> 2 blocks/CU) — unchanged since R5, the R13
// pipeline never fixed it. Change: BK=32, LDS 32KB (2dbuf x [A,B] x 128x32)
// -> 4 blocks/CU (16 waves/CU, launch_bounds(256,4)), grid = exactly 4/CU.
// Same counted-vmcnt 2-deep pipeline (vmcnt(4) = prev tile ready), same
// pre-swizzled gl_lds source; unit swizzle u^=(row>>1)&3 (4 units/row,
// 8 bank-groups per 16-lane phase -> 2-way = free).
// MODE2 epilogue: pid[] hoisted out of ni loop. attn = R13 (119us). Fusion kept.

typedef __attribute__((ext_vector_type(8))) short short8;
typedef __attribute__((ext_vector_type(4))) float floatx4;
typedef unsigned short u16;
typedef unsigned int u32;

__device__ __forceinline__ float bf2f(u16 u){ u32 x=((u32)u)<<16; return __builtin_bit_cast(float,x); }
__device__ __forceinline__ u16 f2bf(float f){ u32 x=__builtin_bit_cast(u32,f); return (u16)((x + 0x7fffu + ((x>>16)&1u))>>16); }

__device__ __forceinline__ floatx4 mfma16(short8 a, short8 b, floatx4 c){
  return __builtin_amdgcn_mfma_f32_16x16x32_bf16(a,b,c,0,0,0);
}

// async global->LDS, 16B per lane. LDS dest = wave-uniform base + lane*16.
__device__ __forceinline__ void gl_lds16(const u16* g, u16* l){
  __builtin_amdgcn_global_load_lds((const __attribute__((address_space(1))) void*)g,
                                   (__attribute__((address_space(3))) void*)l, 16, 0, 0);
}

// ---------- f32 -> bf16 elementwise (for x) ----------
__global__ __launch_bounds__(256)
void k_f2b(const float* __restrict__ in, u16* __restrict__ out, size_t n){
  size_t i = ((size_t)blockIdx.x*256 + threadIdx.x)*4;
  if(i >= n) return;
  float4 v = *(const float4*)(in + i);
  out[i+0] = f2bf(v.x); out[i+1] = f2bf(v.y); out[i+2] = f2bf(v.z); out[i+3] = f2bf(v.w);
}

// ---------- transpose + convert: f32 [K,N] -> bf16 [N,K] ----------
__global__ void k_transpose(const float* __restrict__ in, u16* __restrict__ out, int K, int N){
  __shared__ u16 tile[32][33];
  const int kb = blockIdx.y*32, nb = blockIdx.x*32;
  const int tx = threadIdx.x, ty = threadIdx.y;
#pragma unroll
  for(int i=0;i<4;i++) tile[ty+i*8][tx] = f2bf(in[(size_t)(kb+ty+i*8)*N + nb + tx]);
  __syncthreads();
#pragma unroll
  for(int i=0;i<4;i++) out[(size_t)(nb+ty+i*8)*K + kb + tx] = tile[tx][ty+i*8];
}

// ---------- rope table (fp64 for large-angle accuracy) ----------
__global__ void k_rope_table(float* __restrict__ cosT, float* __restrict__ sinT){
  int idx = blockIdx.x*256 + threadIdx.x;
  if(idx >= 2048*64) return;
  int p = idx>>6, i = idx&63;
  double freq = pow(10000.0, -(double)(2*i)/128.0) * 40.0;
  float ff = (float)freq;
  float ang = (float)((double)p * (double)ff);
  cosT[idx] = (float)cos((double)ang);
  sinT[idx] = (float)sin((double)ang);
}

// ---------- GEMM: A[M,K] bf16 @ Bt[N,K] bf16, BK=32, 4 blocks/CU ----------
// MODE 0: C bf16 [M,N].  MODE 1: C f32 [M,N].
// MODE 2: q epilogue -> q_fin[(b*16+h)*2048+sidx][256], nope*QS / rope.
// MODE 3: kvb epilogue -> k_full (cols<128 of each 256-group) + v_t (cols>=128).
template<int MODE>
__global__ __launch_bounds__(256, 4)
void k_gemm_bt(const u16* __restrict__ A, const u16* __restrict__ Bt, void* __restrict__ Cout,
               int M, int N, int K,
               const int* __restrict__ pid, const float* __restrict__ cosT,
               const float* __restrict__ sinT, u16* __restrict__ out2){
  __shared__ __align__(16) u16 ls[2][2][4096];   // [dbuf][A,B][128*32] = 32 KiB
  const int t = threadIdx.x;
  const int nbx = N>>7;
  const int nwg = gridDim.x;
  const int swz = (blockIdx.x & 7)*(nwg>>3) + (blockIdx.x>>3);
  const int by = swz / nbx, bx = swz - by*nbx;
  const int m0 = by*128, n0 = bx*128;
  const int wv = t>>6, ln = t&63;
  const int wr = (wv>>1)*64, wc = (wv&1)*64;
  const int fr = ln&15, gq = ln>>4;
  // staging: 2 chunks of A + 2 of B, 16B each. chunk j covers LDS bytes
  // o = j*4096 + t*16 -> row = j*64 + (t>>2), unit u = t&3.
  // swizzled source unit = u ^ ((row>>1)&3)  (j*64 doesn't change (row>>1)&3)
  const int srow = t>>2;
  const int su   = (t&3) ^ ((srow>>1)&3);
  const u16* Ag = A + (size_t)(m0 + srow)*K + su*8;
  const u16* Bg = Bt + (size_t)(n0 + srow)*K + su*8;
  const int nt = K>>5;
  // read: global unit gq of row r lives at LDS unit gq^((r>>1)&3); our rows
  // have (r>>1)&3 == (fr>>1)&3 (wr, i*16 are multiples of 8 pairs)
  const int uk = (gq ^ ((fr>>1)&3))*8;
  int raw[4], rbw[4];
#pragma unroll
  for(int i=0;i<4;i++){ raw[i] = (wr+i*16+fr)*32; rbw[i] = (wc+i*16+fr)*32; }

  floatx4 acc[4][4];
#pragma unroll
  for(int i=0;i<4;i++)
#pragma unroll
    for(int j=0;j<4;j++) acc[i][j] = (floatx4){0.f,0.f,0.f,0.f};

  auto stage = [&](int buf, int kt){
    const int k0 = kt*32;
    gl_lds16(Ag + k0,                &ls[buf][0][t*8]);
    gl_lds16(Ag + (size_t)64*K + k0, &ls[buf][0][2048 + t*8]);
    gl_lds16(Bg + k0,                &ls[buf][1][t*8]);
    gl_lds16(Bg + (size_t)64*K + k0, &ls[buf][1][2048 + t*8]);
  };

  // prologue: tiles 0,1 in flight; vmcnt(4) -> tile 0 landed
  stage(0, 0);
  stage(1, 1);
  asm volatile("s_waitcnt vmcnt(4)" ::: "memory");
  __builtin_amdgcn_sched_barrier(0);
  __builtin_amdgcn_s_barrier();
  __builtin_amdgcn_sched_barrier(0);

  for(int kt=0; kt<nt; kt++){
    const int buf = kt&1;
    const u16* LA = &ls[buf][0][0];
    const u16* LB = &ls[buf][1][0];
    __builtin_amdgcn_s_setprio(1);
    {
      short8 af[4], bf[4];
#pragma unroll
      for(int i=0;i<4;i++) af[i] = *(const short8*)&LA[raw[i] + uk];
#pragma unroll
      for(int i=0;i<4;i++) bf[i] = *(const short8*)&LB[rbw[i] + uk];
#pragma unroll
      for(int mi=0;mi<4;mi++)
#pragma unroll
        for(int ni=0;ni<4;ni++) acc[mi][ni] = mfma16(af[mi], bf[ni], acc[mi][ni]);
    }
    __builtin_amdgcn_s_setprio(0);
    if(kt+1 < nt){
      asm volatile("s_waitcnt lgkmcnt(0)" ::: "memory");
      __builtin_amdgcn_sched_barrier(0);
      __builtin_amdgcn_s_barrier();          // all waves done reading buf
      __builtin_amdgcn_sched_barrier(0);
      if(kt+2 < nt){
        stage(buf, kt+2);                    // refill freed buf
        asm volatile("s_waitcnt vmcnt(4)" ::: "memory");   // tile kt+1 ready
      } else {
        asm volatile("s_waitcnt vmcnt(0)" ::: "memory");
      }
      __builtin_amdgcn_sched_barrier(0);
      __builtin_amdgcn_s_barrier();          // tile kt+1 visible to all
      __builtin_amdgcn_sched_barrier(0);
    }
  }

  const int r0 = gq*4, c0 = fr;
  if(MODE <= 1){
#pragma unroll
    for(int mi=0;mi<4;mi++)
#pragma unroll
      for(int ni=0;ni<4;ni++){
        const int row = m0 + wr + mi*16 + r0;
        const int col = n0 + wc + ni*16 + c0;
#pragma unroll
        for(int r=0;r<4;r++){
          float v = acc[mi][ni][r];
          if(MODE==1) ((float*)Cout)[(size_t)(row+r)*N + col] = v;
          else        ((u16*)Cout)[(size_t)(row+r)*N + col] = f2bf(v);
        }
      }
  } else if(MODE == 2){
    // q_fin epilogue. col = n0+wc+ni*16+c0; h = col>>8; d = col&255.
    // block uniform: rope iff (n0&128)!=0.
    const float QS = (float)(0.08838834764831845 * 1.4426950408889634);
    u16* qf = (u16*)Cout;
    const bool rope = (n0 & 128) != 0;
#pragma unroll
    for(int mi=0;mi<4;mi++){
      const int row = m0 + wr + mi*16 + r0;
      int pv[4];
#pragma unroll
      for(int r=0;r<4;r++) pv[r] = rope ? pid[(row+r)&2047] : 0;
#pragma unroll
      for(int ni=0;ni<4;ni++){
        const int col = n0 + wc + ni*16 + c0;
        const int h = col>>8, d = col&255;
#pragma unroll
        for(int r=0;r<4;r++){
          const int tok = row + r;
          const int b = tok>>11, sidx = tok&2047;
          float v = acc[mi][ni][r];
          float res;
          if(rope){
            const int i = (d-128)>>1;
            float c = cosT[pv[r]*64+i], sn = sinT[pv[r]*64+i];
            float partner = __shfl_xor(v, 1);
            if((c0&1)==0) res = v*c - partner*sn;   // xr = v, xi = partner
            else          res = partner*sn + v*c;   // xr = partner, xi = v
          } else {
            res = v;
          }
          qf[(((size_t)(b*16 + h))*2048 + sidx)*256 + d] = f2bf(res*QS);
        }
      }
    }
  } else {
    // MODE 3: kvb epilogue. col = kvh*256 + dd. k_nope iff (n0&128)==0.
    u16* kfull = (u16*)Cout;   // [b][kvh][s][256], dd<128 region
    const bool isv = (n0 & 128) != 0;
#pragma unroll
    for(int mi=0;mi<4;mi++)
#pragma unroll
      for(int ni=0;ni<4;ni++){
        const int row = m0 + wr + mi*16 + r0;
        const int col = n0 + wc + ni*16 + c0;
        const int kvh = (col>>8)&7, dd = col&255;
        if(!isv){
#pragma unroll
          for(int r=0;r<4;r++){
            const int tok = row + r;
            const int b = tok>>11, sidx = tok&2047;
            kfull[(((size_t)(b*8 + kvh))*2048 + sidx)*256 + dd] = f2bf(acc[mi][ni][r]);
          }
        } else {
          // v_t[((bk*64 + kt)*128 + hd)*32 + kv], 4 consecutive kv -> u16x4
          const int tok = row;           // rows row..row+3 share tile (kv%4==0)
          const int b = tok>>11, sidx = tok&2047;
          const int kt = sidx>>5, kv = sidx&31;
          const int hd = dd - 128;
          const size_t base = (((size_t)(b*8 + kvh)*64 + kt)*128 + hd)*32 + kv;
          u32 lo = (u32)f2bf(acc[mi][ni][0]) | ((u32)f2bf(acc[mi][ni][1])<<16);
          u32 hi = (u32)f2bf(acc[mi][ni][2]) | ((u32)f2bf(acc[mi][ni][3])<<16);
          uint2 pk; pk.x = lo; pk.y = hi;
          *(uint2*)&out2[base] = pk;
        }
      }
  }
}

// ---------- layernorm(kv[:512]) -> bf16 ; rope(kv[512:640]) -> k_pe bf16 ----------
__global__ __launch_bounds__(256)
void k_ln_rope(const float* __restrict__ kv, const float* __restrict__ scale,
               const int* __restrict__ pid, const float* __restrict__ cosT,
               const float* __restrict__ sinT, u16* __restrict__ kv_cn, u16* __restrict__ k_pe){
  const int tok = blockIdx.x;
  const int t = threadIdx.x;
  const float* row = kv + (size_t)tok*640;
  float v0 = row[2*t], v1 = row[2*t+1];
  float s = v0+v1, ss = v0*v0+v1*v1;
#pragma unroll
  for(int off=32; off>=1; off>>=1){ s += __shfl_xor(s,off); ss += __shfl_xor(ss,off); }
  __shared__ float red[8];
  if((t&63)==0){ red[t>>6]=s; red[4+(t>>6)]=ss; }
  __syncthreads();
  float S4 = red[0]+red[1]+red[2]+red[3];
  float SS4 = red[4]+red[5]+red[6]+red[7];
  float mean = S4*(1.f/512.f);
  float var = SS4*(1.f/512.f) - mean*mean;
  float inv = rsqrtf(var + 1e-5f);
  kv_cn[(size_t)tok*512 + 2*t]   = f2bf((v0-mean)*inv*scale[2*t]);
  kv_cn[(size_t)tok*512 + 2*t+1] = f2bf((v1-mean)*inv*scale[2*t+1]);
  if(t < 128){
    const int sidx = tok & 2047;
    const int p = pid[sidx];
    const int i = t>>1;
    float c = cosT[p*64+i], sn = sinT[p*64+i];
    float xr = row[512+2*i], xi = row[512+2*i+1];
    float val = (t&1) ? (xr*sn + xi*c) : (xr*c - xi*sn);
    k_pe[(size_t)tok*128 + t] = f2bf(val);
  }
}

// ---------- fill k_full[..][128..256) from k_pe ----------
__global__ __launch_bounds__(128)
void k_pefill(const u16* __restrict__ k_pe, u16* __restrict__ k_full){
  const int tok = blockIdx.x;
  const int b = tok>>11, sidx = tok&2047;
  const int t = threadIdx.x;
  const int kh = t>>4, seg = t&15;
  short8 v = *(const short8*)(k_pe + (size_t)tok*128 + seg*8);
  *(short8*)(k_full + (((size_t)(b*8 + kh))*2048 + sidx)*256 + 128 + seg*8) = v;
}

// ---------- flash attention (R13 verbatim): XCD-swizzled, balanced, m=2 ----------
__global__ __launch_bounds__(128, 2)
void k_attn(const u16* __restrict__ q_fin, const u16* __restrict__ k_full,
            const u16* __restrict__ v_t, u16* __restrict__ attn){
  __shared__ __align__(16) u16 lsK[2*8192];   // 32768 B : 2 x [32][256] swizzled
  __shared__ __align__(16) u16 lsP[2*32*40];  //  5120 B : per-wave [32][40]
  const int blk = blockIdx.x;
  const int kvh = blk&7;
  const int i  = blk>>3;          // 0..127
  const int j  = i>>5;            // 0..3
  const int mm = i&31;
  const int s  = mm>>2;           // 0..7
  int qt;
  if(j==0)      qt = s;
  else if(j==1) qt = 31 - s;
  else if(j==2) qt = 8 + s;
  else          qt = 23 - s;
  const int bb = (mm>>1)&1;
  const int hp = mm&1;
  const int h  = kvh*2 + hp;
  const int t = threadIdx.x, wv = t>>6, ln = t&63;
  const int fq = ln&15, gq = ln>>4;
  const u16* kbase = k_full + ((size_t)(bb*8 + kvh))*2048*256;
  const u16* vbase = v_t + ((size_t)(bb*8 + kvh))*128*2048;
  u16* Pw = &lsP[wv*32*40];

  int soff[8];
#pragma unroll
  for(int s8=0;s8<8;s8++){
    int o = s8*2048 + t*16;
    int row = o>>9, colb = o&511;
    soff[s8] = row*512 + (colb ^ ((row&7)<<4));
  }
  const int swz = (fq&7)<<4;
  int cb[8];
#pragma unroll
  for(int c=0;c<8;c++) cb[c] = (gq*16 + c*64) ^ swz;
  const int rowb = fq*512;
  const u16* vfp = vbase + (size_t)fq*32 + gq*8;

  const int last = 2*qt + 1;
  short8 qf[2][8];
#pragma unroll
  for(int m=0;m<2;m++){
    const u16* qb = q_fin + (((size_t)(bb*16 + h))*2048 + qt*64 + wv*32 + m*16 + fq)*256;
#pragma unroll
    for(int c=0;c<8;c++) qf[m][c] = *(const short8*)(qb + c*32 + gq*8);
  }
  floatx4 oacc[2][8];
#pragma unroll
  for(int m=0;m<2;m++)
#pragma unroll
    for(int ii=0;ii<8;ii++) oacc[m][ii] = (floatx4){0.f,0.f,0.f,0.f};
  float mprev0 = -3e38f, mprev1 = -3e38f, lsum0 = 0.f, lsum1 = 0.f;

#pragma unroll
  for(int s8=0;s8<8;s8++)
    gl_lds16((const u16*)((const char*)kbase + soff[s8]), &lsK[s8*1024 + wv*512]);
  __syncthreads();

  int cur = 0;
  for(int kt=0; kt<=last; kt++){
    if(kt < last){
      const char* ktile = (const char*)kbase + (size_t)(kt+1)*16384;
      u16* kdst = &lsK[(cur^1)*8192];
#pragma unroll
      for(int s8=0;s8<8;s8++)
        gl_lds16((const u16*)(ktile + soff[s8]), kdst + s8*1024 + wv*512);
    }
    short8 vf[8];
#pragma unroll
    for(int hs=0;hs<8;hs++)
      vf[hs] = *(const short8*)(vfp + (size_t)kt*4096 + hs*512);

    const char* Kc = (const char*)lsK + cur*16384;
    floatx4 sc[2][2];
#pragma unroll
    for(int m=0;m<2;m++)
#pragma unroll
      for(int ns=0;ns<2;ns++) sc[m][ns] = (floatx4){0.f,0.f,0.f,0.f};
#pragma unroll
    for(int ns=0;ns<2;ns++){
#pragma unroll
      for(int c=0;c<8;c++){
        short8 kf = *(const short8*)(Kc + ns*8192 + rowb + cb[c]);
        sc[0][ns] = mfma16(kf, qf[0][c], sc[0][ns]);
        sc[1][ns] = mfma16(kf, qf[1][c], sc[1][ns]);
      }
    }
    if(kt >= 2*qt){
      const int off = (kt - 2*qt)*32;
#pragma unroll
      for(int m=0;m<2;m++){
        const int qloc = wv*32 + m*16 + fq;
#pragma unroll
        for(int ns=0;ns<2;ns++)
#pragma unroll
          for(int r=0;r<4;r++)
            if(off + ns*16 + gq*4 + r > qloc) sc[m][ns][r] = -1e30f;
      }
    }
    float ml0 = -3e38f, ml1 = -3e38f;
#pragma unroll
    for(int ns=0;ns<2;ns++)
#pragma unroll
      for(int r=0;r<4;r++){ ml0 = fmaxf(ml0, sc[0][ns][r]); ml1 = fmaxf(ml1, sc[1][ns][r]); }
    ml0 = fmaxf(ml0, __shfl_xor(ml0, 16)); ml0 = fmaxf(ml0, __shfl_xor(ml0, 32));
    ml1 = fmaxf(ml1, __shfl_xor(ml1, 16)); ml1 = fmaxf(ml1, __shfl_xor(ml1, 32));
    if(__any((ml0 > mprev0 + 8.f) || (ml1 > mprev1 + 8.f))){
      const float mn0 = fmaxf(mprev0, ml0), mn1 = fmaxf(mprev1, ml1);
      const float a0 = exp2f(mprev0 - mn0), a1 = exp2f(mprev1 - mn1);
      lsum0 *= a0; lsum1 *= a1;
      float aO0[4], aO1[4];
#pragma unroll
      for(int r=0;r<4;r++){ aO0[r] = __shfl(a0, gq*4 + r); aO1[r] = __shfl(a1, gq*4 + r); }
#pragma unroll
      for(int hs=0;hs<8;hs++)
#pragma unroll
        for(int r=0;r<4;r++){ oacc[0][hs][r] *= aO0[r]; oacc[1][hs][r] *= aO1[r]; }
      mprev0 = mn0; mprev1 = mn1;
    }
    float ps0 = 0.f, ps1 = 0.f;
#pragma unroll
    for(int ns=0;ns<2;ns++)
#pragma unroll
      for(int r=0;r<4;r++){
        float p0 = exp2f(sc[0][ns][r] - mprev0);
        float p1 = exp2f(sc[1][ns][r] - mprev1);
        sc[0][ns][r] = p0; sc[1][ns][r] = p1;
        ps0 += p0; ps1 += p1;
      }
    ps0 += __shfl_xor(ps0, 16); ps0 += __shfl_xor(ps0, 32);
    ps1 += __shfl_xor(ps1, 16); ps1 += __shfl_xor(ps1, 32);
    lsum0 += ps0; lsum1 += ps1;

#pragma unroll
    for(int m=0;m<2;m++)
#pragma unroll
      for(int ns=0;ns<2;ns++){
        u32 p01, p23;
        asm("v_cvt_pk_bf16_f32 %0, %1, %2" : "=v"(p01) : "v"(sc[m][ns][0]), "v"(sc[m][ns][1]));
        asm("v_cvt_pk_bf16_f32 %0, %1, %2" : "=v"(p23) : "v"(sc[m][ns][2]), "v"(sc[m][ns][3]));
        uint2 pk; pk.x = p01; pk.y = p23;
        *(uint2*)&Pw[(m*16 + fq)*40 + ns*16 + gq*4] = pk;
      }
    __builtin_amdgcn_s_waitcnt(0xC07F);  // lgkmcnt(0): P visible to own wave

#pragma unroll
    for(int m=0;m<2;m++){
      short8 pa = *(const short8*)&Pw[(m*16 + fq)*40 + gq*8];
#pragma unroll
      for(int hs=0;hs<8;hs++)
        oacc[m][hs] = mfma16(pa, vf[hs], oacc[m][hs]);
    }
    __syncthreads();
    cur ^= 1;
  }
  const float i0 = 1.f / lsum0, i1 = 1.f / lsum1;
  float iO0[4], iO1[4];
#pragma unroll
  for(int r=0;r<4;r++){ iO0[r] = __shfl(i0, gq*4 + r); iO1[r] = __shfl(i1, gq*4 + r); }
#pragma unroll
  for(int m=0;m<2;m++)
#pragma unroll
    for(int hs=0;hs<8;hs++)
#pragma unroll
      for(int r=0;r<4;r++){
        const int qi = qt*64 + wv*32 + m*16 + gq*4 + r;
        float sc_ = (m==0) ? iO0[r] : iO1[r];
        attn[(((size_t)(bb*2048 + qi))*16 + h)*128 + hs*16 + fq] = f2bf(oacc[m][hs][r]*sc_);
      }
}

extern "C" void kernel_launch(void* const* d_in, const int* in_sizes, int n_in,
                              void* d_out, int out_size, void* d_ws, size_t ws_size,
                              hipStream_t stream){
  const float* x    = (const float*)d_in[0];
  const float* wq   = (const float*)d_in[1];
  const float* wkva = (const float*)d_in[2];
  const float* kvsc = (const float*)d_in[3];
  const float* wkvb = (const float*)d_in[4];
  const float* wo   = (const float*)d_in[5];
  const int* pid  = (const int*)d_in[7];
  float* out = (float*)d_out;

  char* w = (char*)d_ws;
  size_t off = 0;
  auto alloc = [&](size_t bytes)->void*{
    void* p = (void*)(w + off);
    off += (bytes + 255) & ~(size_t)255;
    return p;
  };
  u16*   x_bf   = (u16*)alloc((size_t)4096*2048*2);
  u16*   wq_t   = (u16*)alloc((size_t)4096*2048*2);
  u16*   wkva_t = (u16*)alloc((size_t)640*2048*2);
  u16*   wkvb_t = (u16*)alloc((size_t)2048*512*2);
  u16*   wo_t   = (u16*)alloc((size_t)2048*2048*2);
  float* cosT   = (float*)alloc((size_t)2048*64*4);
  float* sinT   = (float*)alloc((size_t)2048*64*4);
  float* kvf    = (float*)alloc((size_t)4096*640*4);
  u16*   kv_cn  = (u16*)alloc((size_t)4096*512*2);
  u16*   k_pe   = (u16*)alloc((size_t)4096*128*2);
  u16*   q_fin  = (u16*)alloc((size_t)4096*4096*2);
  u16*   k_full = (u16*)alloc((size_t)2*8*2048*256*2);
  u16*   v_t    = (u16*)alloc((size_t)2*8*128*2048*2);
  u16*   attn   = (u16*)alloc((size_t)4096*2048*2);

  k_f2b<<<8192, 256, 0, stream>>>(x, x_bf, (size_t)4096*2048);
  k_transpose<<<dim3(128, 64), dim3(32,8), 0, stream>>>(wq,   wq_t,   2048, 4096);
  k_transpose<<<dim3(20,  64), dim3(32,8), 0, stream>>>(wkva, wkva_t, 2048, 640);
  k_transpose<<<dim3(64,  16), dim3(32,8), 0, stream>>>(wkvb, wkvb_t, 512,  2048);
  k_transpose<<<dim3(64,  64), dim3(32,8), 0, stream>>>(wo,   wo_t,   2048, 2048);
  k_rope_table<<<512, 256, 0, stream>>>(cosT, sinT);

  // q projection + rope + layout, fused
  k_gemm_bt<2><<<1024, 256, 0, stream>>>(x_bf, wq_t, q_fin, 4096, 4096, 2048,
                                         pid, cosT, sinT, nullptr);
  k_gemm_bt<1><<<160,  256, 0, stream>>>(x_bf, wkva_t, kvf, 4096, 640, 2048,
                                         nullptr, nullptr, nullptr, nullptr);
  k_ln_rope<<<4096, 256, 0, stream>>>(kvf, kvsc, pid, cosT, sinT, kv_cn, k_pe);
  // kv_b projection + k_full/v_t scatter, fused
  k_gemm_bt<3><<<512,  256, 0, stream>>>(kv_cn, wkvb_t, k_full, 4096, 2048, 512,
                                         nullptr, nullptr, nullptr, v_t);
  k_pefill<<<4096, 128, 0, stream>>>(k_pe, k_full);
  k_attn<<<1024, 128, 0, stream>>>(q_fin, k_full, v_t, attn);
  k_gemm_bt<1><<<512,  256, 0, stream>>>(attn, wo_t, out, 4096, 2048, 2048,
                                         nullptr, nullptr, nullptr, nullptr);
}